// Round 1
// baseline (125.811 us; speedup 1.0000x reference)
//
#include <hip/hip_runtime.h>

#define BB 8
#define NN 256
#define DD 128
#define OC 128   // OUT

// ---------------------------------------------------------------------------
// Kernel 1: per-node precompute.
//   preA[b,i,k] = sum_d h[b,i,d] * Wm1[d,k]          (h_i contribution)
//   preB[b,j,k] = sum_d h[b,j,d] * Wm1[128+d,k]      (h_j contribution)
//   ai[b,i]    = sum_d h[b,i,d] * Wa[d]
//   aj[b,j]    = sum_d h[b,j,d] * Wa[128+d]
// ---------------------------------------------------------------------------
__global__ __launch_bounds__(128) void precompute_kernel(
    const float* __restrict__ h, const float* __restrict__ Wm1,
    const float* __restrict__ Wa,
    float* __restrict__ preA, float* __restrict__ preB,
    float* __restrict__ ai, float* __restrict__ aj)
{
    const int row = blockIdx.x;     // b*NN + node, 0..2047
    const int k   = threadIdx.x;    // 0..127

    __shared__ float hrow[DD];
    hrow[k] = h[row * DD + k];
    __syncthreads();

    float accA = 0.f, accB = 0.f;
    #pragma unroll 8
    for (int d = 0; d < DD; ++d) {
        const float hv = hrow[d];
        accA = fmaf(hv, Wm1[d * OC + k], accA);
        accB = fmaf(hv, Wm1[(DD + d) * OC + k], accB);
    }
    preA[row * OC + k] = accA;
    preB[row * OC + k] = accB;

    // attention dot products (reduce 128 lanes -> scalar)
    float vi = hrow[k] * Wa[k];
    float vj = hrow[k] * Wa[DD + k];
    #pragma unroll
    for (int off = 32; off > 0; off >>= 1) {
        vi += __shfl_down(vi, off, 64);
        vj += __shfl_down(vj, off, 64);
    }
    __shared__ float red[4];
    if ((k & 63) == 0) { red[(k >> 6) * 2] = vi; red[(k >> 6) * 2 + 1] = vj; }
    __syncthreads();
    if (k == 0) { ai[row] = red[0] + red[2]; aj[row] = red[1] + red[3]; }
}

// ---------------------------------------------------------------------------
// Kernel 2: one block per (b, i).  256 threads.
//   Phase A: attention logits over j, masked softmax -> w_sh[j], wsum.
//   Phase B: t[k] = sum_j w_j * relu(preA[i,k] + preB[j,k] + d_ij*Wm1[256,k] + bm1[k])
//            (channel k handled by 2 threads, each covering 128 j's)
//   Phase C: agg[k] = sum_m t[m]*Wm2[m,k] + bm2[k]*wsum
//   Phase D: out[k] = relu( sum_d h[i,d]*Wu[d,k] + sum_m agg[m]*Wu[128+m,k] + bu[k] )
// ---------------------------------------------------------------------------
__global__ __launch_bounds__(256) void gnn_main_kernel(
    const float* __restrict__ h, const int* __restrict__ adj,
    const float* __restrict__ dist,
    const float* __restrict__ Wm1, const float* __restrict__ bm1,
    const float* __restrict__ Wm2, const float* __restrict__ bm2,
    const float* __restrict__ Wa,  const float* __restrict__ ba,
    const float* __restrict__ Wu,  const float* __restrict__ bu,
    const float* __restrict__ preA, const float* __restrict__ preB,
    const float* __restrict__ aiArr, const float* __restrict__ ajArr,
    float* __restrict__ out)
{
    const int row  = blockIdx.x;        // b*NN + i
    const int b    = row >> 8;          // NN = 256
    const int tid  = threadIdx.x;
    const int k    = tid & (OC - 1);    // channel 0..127
    const int half = tid >> 7;          // which j/m half this thread covers

    __shared__ float w_sh[NN];
    __shared__ float d_sh[NN];
    __shared__ float red_sh[256];
    __shared__ float t_sh[OC];
    __shared__ float agg_sh[OC];
    __shared__ float preA_sh[OC];
    __shared__ float hrow_sh[DD];
    __shared__ float wsum_sh;

    // ---- Phase A: masked softmax over j ----
    const int   j  = tid;
    const float dv = dist[row * NN + j];
    const int   mk = adj[row * NN + j];
    d_sh[j] = dv;

    float logit = aiArr[row] + ajArr[b * NN + j] + dv * Wa[2 * DD] + ba[0];
    logit = (logit >= 0.f) ? logit : 0.2f * logit;     // leaky_relu(0.2)
    if (mk == 0) logit = -1e9f;

    red_sh[tid] = logit;
    __syncthreads();
    #pragma unroll
    for (int s = 128; s > 0; s >>= 1) {
        if (tid < s) red_sh[tid] = fmaxf(red_sh[tid], red_sh[tid + s]);
        __syncthreads();
    }
    const float mx = red_sh[0];
    __syncthreads();

    const float e = __expf(logit - mx);
    red_sh[tid] = e;
    __syncthreads();
    #pragma unroll
    for (int s = 128; s > 0; s >>= 1) {
        if (tid < s) red_sh[tid] += red_sh[tid + s];
        __syncthreads();
    }
    const float esum = red_sh[0];
    const float w = mk ? (e / esum) : 0.f;
    w_sh[j] = w;
    __syncthreads();                    // done reading red_sh (esum)

    // wsum reduction; also stage preA row + h row while we're here
    red_sh[tid] = w;
    if (tid < OC)   preA_sh[tid]        = preA[row * OC + tid];
    if (tid >= 128) hrow_sh[tid - 128]  = h[row * DD + (tid - 128)];
    __syncthreads();
    #pragma unroll
    for (int s = 128; s > 0; s >>= 1) {
        if (tid < s) red_sh[tid] += red_sh[tid + s];
        __syncthreads();
    }
    if (tid == 0) wsum_sh = red_sh[0];
    __syncthreads();

    // ---- Phase B: weighted relu accumulation ----
    const float wm1d = Wm1[2 * DD * OC + k];   // d_ij coefficient row
    const float bm1k = bm1[k];
    const float pa   = preA_sh[k];
    const float* __restrict__ pB = preB + b * NN * OC;

    float acc = 0.f;
    const int j0 = half * 128;
    for (int jj = j0; jj < j0 + 128; ++jj) {
        const float wj = w_sh[jj];
        if (wj != 0.f) {                       // wave-uniform skip of masked j
            float val = fmaf(d_sh[jj], wm1d, pa + pB[jj * OC + k]) + bm1k;
            acc = fmaf(wj, fmaxf(val, 0.f), acc);
        }
    }
    red_sh[tid] = acc;
    __syncthreads();
    if (tid < OC) t_sh[tid] = red_sh[tid] + red_sh[tid + 128];
    __syncthreads();

    // ---- Phase C: agg = t @ Wm2 + bm2 * wsum ----
    float aggacc = 0.f;
    const int m0 = half * 64;
    #pragma unroll 4
    for (int m = m0; m < m0 + 64; ++m)
        aggacc = fmaf(t_sh[m], Wm2[m * OC + k], aggacc);
    red_sh[tid] = aggacc;
    __syncthreads();
    if (tid < OC) agg_sh[tid] = red_sh[tid] + red_sh[tid + 128] + bm2[tid] * wsum_sh;
    __syncthreads();

    // ---- Phase D: out = relu( [h, agg] @ Wu + bu ) ----
    float outacc = 0.f;
    if (half == 0) {
        #pragma unroll 4
        for (int d2 = 0; d2 < DD; ++d2)
            outacc = fmaf(hrow_sh[d2], Wu[d2 * OC + k], outacc);
    } else {
        #pragma unroll 4
        for (int m = 0; m < OC; ++m)
            outacc = fmaf(agg_sh[m], Wu[(DD + m) * OC + k], outacc);
    }
    red_sh[tid] = outacc;
    __syncthreads();
    if (tid < OC)
        out[row * OC + tid] = fmaxf(red_sh[tid] + red_sh[tid + 128] + bu[tid], 0.f);
}

extern "C" void kernel_launch(void* const* d_in, const int* in_sizes, int n_in,
                              void* d_out, int out_size, void* d_ws, size_t ws_size,
                              hipStream_t stream) {
    const float* h    = (const float*)d_in[0];
    const int*   adj  = (const int*)  d_in[1];
    const float* dist = (const float*)d_in[2];
    const float* Wm1  = (const float*)d_in[3];
    const float* bm1  = (const float*)d_in[4];
    const float* Wm2  = (const float*)d_in[5];
    const float* bm2  = (const float*)d_in[6];
    const float* Wa   = (const float*)d_in[7];
    const float* ba   = (const float*)d_in[8];
    const float* Wu   = (const float*)d_in[9];
    const float* bu   = (const float*)d_in[10];
    float* out = (float*)d_out;

    float* preA = (float*)d_ws;                 // 2048*128 f32 = 1 MB
    float* preB = preA + BB * NN * OC;          // 1 MB
    float* ai   = preB + BB * NN * OC;          // 8 KB
    float* aj   = ai + BB * NN;                 // 8 KB

    precompute_kernel<<<BB * NN, 128, 0, stream>>>(h, Wm1, Wa, preA, preB, ai, aj);
    gnn_main_kernel<<<BB * NN, 256, 0, stream>>>(h, adj, dist,
                                                 Wm1, bm1, Wm2, bm2, Wa, ba, Wu, bu,
                                                 preA, preB, ai, aj, out);
}